// Round 7
// baseline (419.641 us; speedup 1.0000x reference)
//
#include <hip/hip_runtime.h>
#include <hip/hip_bf16.h>
#include <stdint.h>

#define NN 10000
#define NF 256
#define NSTEPS 313   // ceil(10000/32)
#define NSP 8        // K-split factor

typedef float f32x4 __attribute__((ext_vector_type(4)));
typedef __bf16 bf16x8 __attribute__((ext_vector_type(8)));
typedef unsigned short u16;

__device__ __forceinline__ u16 f2bf(float f) {
    __bf16 h = (__bf16)f;
    return __builtin_bit_cast(u16, h);
}

__device__ __forceinline__ int split_lo(int part) {
    const int base = NSTEPS / NSP, extra = NSTEPS % NSP;
    return part * base + (part < extra ? part : extra);
}

// ---------------- kernel 1: k_prep — adj -> pre-tiled/pre-swizzled bf16 AT + row-sum partials ----
// grid (157, 8). Block (mt,kc): rows [mt*64,+64), K-steps [t0,t1).
// Tile (mt,s): 64 rows x 32 k bf16, 4096 B, row-major 64 B/row; 16-B chunk c of row r
// stored at slot c ^ ((r>>1)&3)  -> k_gemm's ds_read_b128 is 2-way (free).
// Tiles fully written (zeros beyond NN) so k_gemm needs no validity checks on A.
__global__ __launch_bounds__(256) void k_prep(const float* __restrict__ adj,
                                              u16* __restrict__ AT,
                                              float* __restrict__ degp) {
    const int mt = blockIdx.x, kc = blockIdx.y;
    const int m0 = mt * 64;
    const int t = threadIdx.x;
    const int r = t & 63, w = t >> 6;
    const int row = m0 + r;
    const bool rowv = row < NN;
    const float* rowp = adj + (size_t)(rowv ? row : 0) * NN;
    const int t0 = split_lo(kc), t1 = split_lo(kc + 1);
    const int swz = (r >> 1) & 3;

    float psum = 0.f;
    for (int c0 = t0; c0 < t1; c0 += 8) {
#pragma unroll
        for (int j = 0; j < 2; ++j) {
            const int s = c0 + 2 * w + j;
            if (s < t1) {
                const int k0 = s * 32;
                f32x4 v[8];
#pragma unroll
                for (int q = 0; q < 8; ++q) {
                    const int k = k0 + q * 4;
                    if (rowv && k < NN) v[q] = *reinterpret_cast<const f32x4*>(rowp + k);
                    else { v[q][0] = 0.f; v[q][1] = 0.f; v[q][2] = 0.f; v[q][3] = 0.f; }
                }
                f32x4 ss = v[0];
#pragma unroll
                for (int q = 1; q < 8; ++q) ss += v[q];
                psum += (ss[0] + ss[1]) + (ss[2] + ss[3]);

                u16* tb = AT + (size_t)(mt * NSTEPS + s) * 2048 + r * 32;
#pragma unroll
                for (int c = 0; c < 4; ++c) {
                    bf16x8 o;
#pragma unroll
                    for (int e = 0; e < 4; ++e) {
                        o[e]     = (__bf16)v[2 * c][e];
                        o[e + 4] = (__bf16)v[2 * c + 1][e];
                    }
                    *reinterpret_cast<bf16x8*>(tb + ((c ^ swz) * 8)) = o;
                }
            }
        }
    }

    __shared__ float red[4][64];
    red[w][r] = psum;
    __syncthreads();
    if (t < 64 && (m0 + t) < NN) {
        degp[(size_t)kc * NN + m0 + t] = (red[0][t] + red[1][t]) + (red[2][t] + red[3][t]);
    }
}

// ---------------- kernel 1b: dinv = rsqrt(sum of partials) ----------------
__global__ __launch_bounds__(256) void k_dinv(const float* __restrict__ degp,
                                              float* __restrict__ dinv) {
    const int i = blockIdx.x * 256 + threadIdx.x;
    if (i < NN) {
        float d = 0.f;
#pragma unroll
        for (int kc = 0; kc < NSP; ++kc) d += degp[(size_t)kc * NN + i];
        dinv[i] = d > 0.f ? 1.0f / sqrtf(d) : 0.0f;
    }
}

// ---------------- kernel 2: T = feat @ W; SPT = (dinv*T)^T bf16; SELF = 2*dinv^2*T + b ----------------
__global__ __launch_bounds__(256) void k_support(const float* __restrict__ feat,
                                                 const float* __restrict__ W,
                                                 const float* __restrict__ dinv,
                                                 const float* __restrict__ bias,
                                                 u16* __restrict__ SPT,
                                                 float* __restrict__ selfbuf) {
    const int j0 = blockIdx.x * 64;
    const int c0 = blockIdx.y * 64;
    __shared__ float flds[128][64];   // [f][r] transposed, 32 KB
    const int t = threadIdx.x;
    const int rg = t & 15, cg = t >> 4;
    const int sr = t >> 2, sf = (t & 3) * 32;
    float acc[4][4] = {};

    for (int half = 0; half < 2; ++half) {
        __syncthreads();
        const int gj = j0 + sr;
#pragma unroll
        for (int i = 0; i < 8; ++i) {
            f32x4 v = {};
            if (gj < NN)
                v = *reinterpret_cast<const f32x4*>(&feat[(size_t)gj * NF + half * 128 + sf + i * 4]);
#pragma unroll
            for (int u = 0; u < 4; ++u) flds[sf + i * 4 + u][sr] = v[u];
        }
        __syncthreads();
#pragma unroll 4
        for (int f = 0; f < 128; ++f) {
            f32x4 fv = *reinterpret_cast<const f32x4*>(&flds[f][rg * 4]);
            f32x4 wv = *reinterpret_cast<const f32x4*>(&W[(size_t)(half * 128 + f) * NF + c0 + cg * 4]);
#pragma unroll
            for (int r = 0; r < 4; ++r)
#pragma unroll
                for (int c = 0; c < 4; ++c)
                    acc[r][c] = fmaf(fv[r], wv[c], acc[r][c]);
        }
    }

    const int jb = j0 + rg * 4;
    if (jb < NN) {
        const f32x4 bv = *reinterpret_cast<const f32x4*>(&bias[c0 + cg * 4]);
        u16 bits[4][4];
#pragma unroll
        for (int r = 0; r < 4; ++r) {
            const float dv = dinv[jb + r];
            f32x4 init;
#pragma unroll
            for (int c = 0; c < 4; ++c) {
                const float sp = acc[r][c] * dv;          // S' = dinv_j * T
                bits[r][c] = f2bf(sp);
                init[c] = 2.f * dv * sp + bv[c];          // self-term + bias (fp32)
            }
            *reinterpret_cast<f32x4*>(&selfbuf[(size_t)(jb + r) * NF + c0 + cg * 4]) = init;
        }
#pragma unroll
        for (int c = 0; c < 4; ++c) {
            ushort4 v; v.x = bits[0][c]; v.y = bits[1][c]; v.z = bits[2][c]; v.w = bits[3][c];
            *reinterpret_cast<ushort4*>(&SPT[(size_t)(c0 + cg * 4 + c) * NN + jb]) = v;
        }
    }
}

// ---------------- kernel 3: P[ks] = AT(m-tile, k-slice) @ S' ----------------
// Linear grid 157*8: ks = bid&7 (XCD-pinned SPT k-slice in L2), mt = bid>>3.
// A: ONE contiguous 4-KB global_load_lds per step into 3-deep ring; uniform vmcnt(1)
// via clamped dummy issues. B: reg double-buffer from L2-resident SPT. No k-guards on A
// (tiles pre-zeroed); ds_read 2-way-free via the pre-baked XOR slot.
__global__ __launch_bounds__(256, 2) void k_gemm(const u16* __restrict__ AT,
                                                 const u16* __restrict__ SPT,
                                                 float* __restrict__ P) {
    const int bid = blockIdx.x;
    const int ks = bid & 7, mt = bid >> 3;
    const int m0 = mt * 64;
    const int t = threadIdx.x;
    const int lane = t & 63, w = t >> 6;
    const int n0 = w * 64;
    const int lrow = lane & 15, lk = lane >> 4;
    const int swz = (lrow >> 1) & 3;
    const int aslot = (lk ^ swz) * 8;            // u16 offset of this lane's 16-B chunk

    const int s0 = split_lo(ks), s1 = split_lo(ks + 1);

    __shared__ __align__(16) u16 Abuf[3][2048];  // 3 x 4 KB ring

    auto stage = [&](int d, int s) {
        const int su = (s < s1) ? s : (s1 - 1);  // clamp -> dummy keeps vmcnt uniform
        const u16* src = AT + (size_t)(mt * NSTEPS + su) * 2048 + t * 8;
        __builtin_amdgcn_global_load_lds(
            (const __attribute__((address_space(1))) void*)src,
            (__attribute__((address_space(3))) void*)&Abuf[d][t * 8],
            16, 0, 0);
    };

    const u16* bbase = SPT + (size_t)(n0 + lrow) * NN + lk * 8;   // lane k-phase built in
    auto loadB = [&](int s, uint4* bq) {
        const int su = (s < s1) ? s : (s1 - 1);
        const int k0 = su * 32;
        const int kb = ((k0 + lk * 8) < NN) ? k0 : 0;
#pragma unroll
        for (int nf = 0; nf < 4; ++nf)
            bq[nf] = *reinterpret_cast<const uint4*>(bbase + (size_t)nf * 16 * NN + kb);
    };

    f32x4 acc[4][4] = {};
    uint4 bc[4], bn[4];

    // prologue order: stage(s0), loadB(s0), stage(s0+1)  -> uniform vmcnt(1) works
    stage(0, s0);
    loadB(s0, bc);
    stage(1, s0 + 1);

    int dcur = 0;
    for (int s = s0; s < s1; ++s) {
        asm volatile("s_waitcnt vmcnt(1)" ::: "memory");   // stage(s)+loadB(s) landed
        __builtin_amdgcn_s_barrier();

        loadB(s + 1, bn);
        stage(dcur >= 1 ? dcur - 1 : 2, s + 2);            // ring slot (dcur+2)%3

        const bool kv = (s * 32 + lk * 8) < NN;            // B-side garbage guard only
        const bf16x8 zz = (bf16x8)(__bf16)0.0f;
        bf16x8 af[4], bfv[4];
#pragma unroll
        for (int fi = 0; fi < 4; ++fi) {
            af[fi] = *reinterpret_cast<const bf16x8*>(&Abuf[dcur][(fi * 16 + lrow) * 32 + aslot]);
            bfv[fi] = kv ? *reinterpret_cast<const bf16x8*>(&bc[fi]) : zz;
        }
#pragma unroll
        for (int i = 0; i < 4; ++i)
#pragma unroll
            for (int j = 0; j < 4; ++j)
                acc[i][j] = __builtin_amdgcn_mfma_f32_16x16x32_bf16(af[i], bfv[j], acc[i][j], 0, 0, 0);

#pragma unroll
        for (int nf = 0; nf < 4; ++nf) bc[nf] = bn[nf];
        dcur = (dcur + 1 == 3) ? 0 : dcur + 1;
    }
    asm volatile("s_waitcnt vmcnt(0)" ::: "memory");       // drain dummies before LDS dealloc

    // epilogue: plain stores of fp32 partial to slab ks (dinv_i applied in k_out)
    float* Pp = P + (size_t)ks * ((size_t)NN * NF);
#pragma unroll
    for (int i = 0; i < 4; ++i) {
        const int rb = m0 + i * 16 + lk * 4;     // C/D: col=lane&15, row=(lane>>4)*4+reg
#pragma unroll
        for (int r = 0; r < 4; ++r) {
            const int row = rb + r;
            if (row < NN) {
#pragma unroll
                for (int j = 0; j < 4; ++j)
                    Pp[(size_t)row * NF + n0 + j * 16 + lrow] = acc[i][j][r];
            }
        }
    }
}

// ---------------- kernel 4: out = relu(dinv_i * sum_s P_s + SELF) ----------------
__global__ __launch_bounds__(256) void k_out(const float* __restrict__ P,
                                             const float* __restrict__ selfbuf,
                                             const float* __restrict__ dinv,
                                             float* __restrict__ out) {
    const size_t e = ((size_t)blockIdx.x * 256 + threadIdx.x) * 4;
    const int row = (int)(e >> 8);
    f32x4 sum = {};
#pragma unroll
    for (int s = 0; s < NSP; ++s)
        sum += *reinterpret_cast<const f32x4*>(&P[(size_t)s * NN * NF + e]);
    const float dv = dinv[row];
    const f32x4 sf = *reinterpret_cast<const f32x4*>(&selfbuf[e]);
    f32x4 o;
#pragma unroll
    for (int c = 0; c < 4; ++c) o[c] = fmaxf(fmaf(dv, sum[c], sf[c]), 0.f);
    *reinterpret_cast<f32x4*>(&out[e]) = o;
}

extern "C" void kernel_launch(void* const* d_in, const int* in_sizes, int n_in,
                              void* d_out, int out_size, void* d_ws, size_t ws_size,
                              hipStream_t stream) {
    const float* adj  = (const float*)d_in[0];
    const float* feat = (const float*)d_in[1];
    const float* W    = (const float*)d_in[2];
    const float* bias = (const float*)d_in[3];
    // d_in[4] (a) is mathematically unused: softmax over a size-1 axis == 1.

    char* ws = (char*)d_ws;
    const size_t AT_OFF   = 0;                       // 157*313*4096 = 201,281,536 B
    const size_t SPT_OFF  = 201281536;               // + 5,120,000 B
    const size_t DEGP_OFF = 206401536;               // + 320,000 B
    const size_t DINV_OFF = 206721536;               // + 40,000 B
    const size_t SELF_OFF = 206761536;               // + 10,240,000 B
    const size_t P_OFF    = 217001536;               // + 81,920,000 B  (~299 MB total; ws ~1.6 GB)
    u16*   AT      = (u16*)(ws + AT_OFF);
    u16*   SPT     = (u16*)(ws + SPT_OFF);
    float* degp    = (float*)(ws + DEGP_OFF);
    float* dinv    = (float*)(ws + DINV_OFF);
    float* selfbuf = (float*)(ws + SELF_OFF);
    float* P       = (float*)(ws + P_OFF);

    k_prep<<<dim3(157, NSP), 256, 0, stream>>>(adj, AT, degp);
    k_dinv<<<40, 256, 0, stream>>>(degp, dinv);
    k_support<<<dim3(157, 4), 256, 0, stream>>>(feat, W, dinv, bias, SPT, selfbuf);
    k_gemm<<<157 * NSP, 256, 0, stream>>>(AT, SPT, P);
    k_out<<<2500, 256, 0, stream>>>(P, selfbuf, dinv, (float*)d_out);
}

// Round 8
// 349.288 us; speedup vs baseline: 1.2014x; 1.2014x over previous
//
#include <hip/hip_runtime.h>
#include <hip/hip_bf16.h>
#include <stdint.h>

#define NN 10000
#define NF 256
#define NSTEPS 313   // ceil(10000/32)
#define NSP 8        // K-split factor

typedef float f32x4 __attribute__((ext_vector_type(4)));
typedef __bf16 bf16x8 __attribute__((ext_vector_type(8)));
typedef unsigned short u16;

__device__ __forceinline__ u16 f2bf(float f) {
    __bf16 h = (__bf16)f;
    return __builtin_bit_cast(u16, h);
}

__device__ __forceinline__ int split_lo(int part) {
    const int base = NSTEPS / NSP, extra = NSTEPS % NSP;
    return part * base + (part < extra ? part : extra);
}

// ---------------- kernel 1: k_prep — adj -> pre-tiled/pre-swizzled bf16 AT + row-sum partials ----
// grid (157, 8). Block (mt,kc): rows [mt*64,+64), K-steps [t0,t1) (39 or 40 steps ~ 5 KB/row).
// WAVE-PER-ROW: each wave-load instr reads 1024 B CONTIGUOUS within one row (the >=1KB
// HBM-efficiency threshold measured across R4-R7). Wave w handles rows w,4+w,...,60+w.
// Lane l of a chunk-load covers step s = t0+ch*8+(l>>3), k = s*32+(l&7)*4.
// Tile layout (matches k_gemm): tile (mt,s) = 64 rows x 32 k bf16, 64 B/row; 16-B chunk
// c of row r at slot c ^ ((r>>1)&3). Tiles fully written (zeros beyond NN).
__global__ __launch_bounds__(256) void k_prep(const float* __restrict__ adj,
                                              u16* __restrict__ AT,
                                              float* __restrict__ degp) {
    const int mt = blockIdx.x, kc = blockIdx.y;
    const int m0 = mt * 64;
    const int t = threadIdx.x;
    const int l = t & 63, w = t >> 6;
    const int t0 = split_lo(kc), t1 = split_lo(kc + 1);

    const int sub = l >> 3;          // step-within-chunk
    const int kofs = (l & 7) * 4;    // float offset within step
    const int c = (l & 7) >> 1;      // 16-B chunk within tile row
    const int h = l & 1;             // 8-B half within chunk

    for (int i = 0; i < 16; ++i) {
        const int r = i * 4 + w;
        const int row = m0 + r;
        const bool rowv = row < NN;
        const float* rowp = adj + (size_t)(rowv ? row : 0) * NN;
        const int swz = (r >> 1) & 3;
        float psum = 0.f;
#pragma unroll
        for (int ch = 0; ch < 5; ++ch) {
            const int s = t0 + ch * 8 + sub;
            const bool sv = s < t1;
            const int k = s * 32 + kofs;
            f32x4 v = {};
            if (rowv && sv && k < NN)
                v = *reinterpret_cast<const f32x4*>(rowp + k);
            psum += (v[0] + v[1]) + (v[2] + v[3]);
            if (sv) {
                ushort4 o;
                o.x = f2bf(v[0]); o.y = f2bf(v[1]); o.z = f2bf(v[2]); o.w = f2bf(v[3]);
                *reinterpret_cast<ushort4*>(
                    AT + (size_t)(mt * NSTEPS + s) * 2048 + r * 32 + (c ^ swz) * 8 + h * 4) = o;
            }
        }
#pragma unroll
        for (int off = 32; off > 0; off >>= 1) psum += __shfl_down(psum, off, 64);
        if (l == 0 && rowv) degp[(size_t)kc * NN + row] = psum;
    }
}

// ---------------- kernel 1b: dinv = rsqrt(sum of partials) ----------------
__global__ __launch_bounds__(256) void k_dinv(const float* __restrict__ degp,
                                              float* __restrict__ dinv) {
    const int i = blockIdx.x * 256 + threadIdx.x;
    if (i < NN) {
        float d = 0.f;
#pragma unroll
        for (int kc = 0; kc < NSP; ++kc) d += degp[(size_t)kc * NN + i];
        dinv[i] = d > 0.f ? 1.0f / sqrtf(d) : 0.0f;
    }
}

// ---------------- kernel 2: T = feat @ W; SPT = (dinv*T)^T bf16; SELF = 2*dinv^2*T + b ----------------
__global__ __launch_bounds__(256) void k_support(const float* __restrict__ feat,
                                                 const float* __restrict__ W,
                                                 const float* __restrict__ dinv,
                                                 const float* __restrict__ bias,
                                                 u16* __restrict__ SPT,
                                                 float* __restrict__ selfbuf) {
    const int j0 = blockIdx.x * 64;
    const int c0 = blockIdx.y * 64;
    __shared__ float flds[128][64];   // [f][r] transposed, 32 KB
    const int t = threadIdx.x;
    const int rg = t & 15, cg = t >> 4;
    const int sr = t >> 2, sf = (t & 3) * 32;
    float acc[4][4] = {};

    for (int half = 0; half < 2; ++half) {
        __syncthreads();
        const int gj = j0 + sr;
#pragma unroll
        for (int i = 0; i < 8; ++i) {
            f32x4 v = {};
            if (gj < NN)
                v = *reinterpret_cast<const f32x4*>(&feat[(size_t)gj * NF + half * 128 + sf + i * 4]);
#pragma unroll
            for (int u = 0; u < 4; ++u) flds[sf + i * 4 + u][sr] = v[u];
        }
        __syncthreads();
#pragma unroll 4
        for (int f = 0; f < 128; ++f) {
            f32x4 fv = *reinterpret_cast<const f32x4*>(&flds[f][rg * 4]);
            f32x4 wv = *reinterpret_cast<const f32x4*>(&W[(size_t)(half * 128 + f) * NF + c0 + cg * 4]);
#pragma unroll
            for (int r = 0; r < 4; ++r)
#pragma unroll
                for (int c = 0; c < 4; ++c)
                    acc[r][c] = fmaf(fv[r], wv[c], acc[r][c]);
        }
    }

    const int jb = j0 + rg * 4;
    if (jb < NN) {
        const f32x4 bv = *reinterpret_cast<const f32x4*>(&bias[c0 + cg * 4]);
        u16 bits[4][4];
#pragma unroll
        for (int r = 0; r < 4; ++r) {
            const float dv = dinv[jb + r];
            f32x4 init;
#pragma unroll
            for (int c = 0; c < 4; ++c) {
                const float sp = acc[r][c] * dv;          // S' = dinv_j * T
                bits[r][c] = f2bf(sp);
                init[c] = 2.f * dv * sp + bv[c];          // self-term + bias (fp32)
            }
            *reinterpret_cast<f32x4*>(&selfbuf[(size_t)(jb + r) * NF + c0 + cg * 4]) = init;
        }
#pragma unroll
        for (int c = 0; c < 4; ++c) {
            ushort4 v; v.x = bits[0][c]; v.y = bits[1][c]; v.z = bits[2][c]; v.w = bits[3][c];
            *reinterpret_cast<ushort4*>(&SPT[(size_t)(c0 + cg * 4 + c) * NN + jb]) = v;
        }
    }
}

// ---------------- kernel 3: P[ks] = AT(m-tile, k-slice) @ S' ----------------
// Linear grid 157*8: ks = bid&7 (XCD-pinned SPT k-slice in L2), mt = bid>>3.
// A: ONE contiguous 4-KB global_load_lds per step into 3-deep ring; uniform vmcnt(1)
// via clamped dummy issues. B: reg double-buffer from L2-resident SPT.
__global__ __launch_bounds__(256, 2) void k_gemm(const u16* __restrict__ AT,
                                                 const u16* __restrict__ SPT,
                                                 float* __restrict__ P) {
    const int bid = blockIdx.x;
    const int ks = bid & 7, mt = bid >> 3;
    const int m0 = mt * 64;
    const int t = threadIdx.x;
    const int lane = t & 63, w = t >> 6;
    const int n0 = w * 64;
    const int lrow = lane & 15, lk = lane >> 4;
    const int swz = (lrow >> 1) & 3;
    const int aslot = (lk ^ swz) * 8;            // u16 offset of this lane's 16-B chunk

    const int s0 = split_lo(ks), s1 = split_lo(ks + 1);

    __shared__ __align__(16) u16 Abuf[3][2048];  // 3 x 4 KB ring

    auto stage = [&](int d, int s) {
        const int su = (s < s1) ? s : (s1 - 1);  // clamp -> dummy keeps vmcnt uniform
        const u16* src = AT + (size_t)(mt * NSTEPS + su) * 2048 + t * 8;
        __builtin_amdgcn_global_load_lds(
            (const __attribute__((address_space(1))) void*)src,
            (__attribute__((address_space(3))) void*)&Abuf[d][t * 8],
            16, 0, 0);
    };

    const u16* bbase = SPT + (size_t)(n0 + lrow) * NN + lk * 8;   // lane k-phase built in
    auto loadB = [&](int s, uint4* bq) {
        const int su = (s < s1) ? s : (s1 - 1);
        const int k0 = su * 32;
        const int kb = ((k0 + lk * 8) < NN) ? k0 : 0;
#pragma unroll
        for (int nf = 0; nf < 4; ++nf)
            bq[nf] = *reinterpret_cast<const uint4*>(bbase + (size_t)nf * 16 * NN + kb);
    };

    f32x4 acc[4][4] = {};
    uint4 bc[4], bn[4];

    stage(0, s0);
    loadB(s0, bc);
    stage(1, s0 + 1);

    int dcur = 0;
    for (int s = s0; s < s1; ++s) {
        asm volatile("s_waitcnt vmcnt(1)" ::: "memory");   // stage(s)+loadB(s) landed
        __builtin_amdgcn_s_barrier();

        loadB(s + 1, bn);
        stage(dcur >= 1 ? dcur - 1 : 2, s + 2);            // ring slot (dcur+2)%3

        const bool kv = (s * 32 + lk * 8) < NN;            // B-side garbage guard only
        const bf16x8 zz = (bf16x8)(__bf16)0.0f;
        bf16x8 af[4], bfv[4];
#pragma unroll
        for (int fi = 0; fi < 4; ++fi) {
            af[fi] = *reinterpret_cast<const bf16x8*>(&Abuf[dcur][(fi * 16 + lrow) * 32 + aslot]);
            bfv[fi] = kv ? *reinterpret_cast<const bf16x8*>(&bc[fi]) : zz;
        }
#pragma unroll
        for (int i = 0; i < 4; ++i)
#pragma unroll
            for (int j = 0; j < 4; ++j)
                acc[i][j] = __builtin_amdgcn_mfma_f32_16x16x32_bf16(af[i], bfv[j], acc[i][j], 0, 0, 0);

#pragma unroll
        for (int nf = 0; nf < 4; ++nf) bc[nf] = bn[nf];
        dcur = (dcur + 1 == 3) ? 0 : dcur + 1;
    }
    asm volatile("s_waitcnt vmcnt(0)" ::: "memory");       // drain dummies before LDS dealloc

    // epilogue: plain stores of fp32 partial to slab ks (dinv_i applied in k_out)
    float* Pp = P + (size_t)ks * ((size_t)NN * NF);
#pragma unroll
    for (int i = 0; i < 4; ++i) {
        const int rb = m0 + i * 16 + lk * 4;     // C/D: col=lane&15, row=(lane>>4)*4+reg
#pragma unroll
        for (int r = 0; r < 4; ++r) {
            const int row = rb + r;
            if (row < NN) {
#pragma unroll
                for (int j = 0; j < 4; ++j)
                    Pp[(size_t)row * NF + n0 + j * 16 + lrow] = acc[i][j][r];
            }
        }
    }
}

// ---------------- kernel 4: out = relu(dinv_i * sum_s P_s + SELF) ----------------
__global__ __launch_bounds__(256) void k_out(const float* __restrict__ P,
                                             const float* __restrict__ selfbuf,
                                             const float* __restrict__ dinv,
                                             float* __restrict__ out) {
    const size_t e = ((size_t)blockIdx.x * 256 + threadIdx.x) * 4;
    const int row = (int)(e >> 8);
    f32x4 sum = {};
#pragma unroll
    for (int s = 0; s < NSP; ++s)
        sum += *reinterpret_cast<const f32x4*>(&P[(size_t)s * NN * NF + e]);
    const float dv = dinv[row];
    const f32x4 sf = *reinterpret_cast<const f32x4*>(&selfbuf[e]);
    f32x4 o;
#pragma unroll
    for (int c = 0; c < 4; ++c) o[c] = fmaxf(fmaf(dv, sum[c], sf[c]), 0.f);
    *reinterpret_cast<f32x4*>(&out[e]) = o;
}

extern "C" void kernel_launch(void* const* d_in, const int* in_sizes, int n_in,
                              void* d_out, int out_size, void* d_ws, size_t ws_size,
                              hipStream_t stream) {
    const float* adj  = (const float*)d_in[0];
    const float* feat = (const float*)d_in[1];
    const float* W    = (const float*)d_in[2];
    const float* bias = (const float*)d_in[3];
    // d_in[4] (a) is mathematically unused: softmax over a size-1 axis == 1.

    char* ws = (char*)d_ws;
    const size_t AT_OFF   = 0;                       // 157*313*4096 = 201,281,536 B
    const size_t SPT_OFF  = 201281536;               // + 5,120,000 B
    const size_t DEGP_OFF = 206401536;               // + 320,000 B
    const size_t DINV_OFF = 206721536;               // + 40,000 B
    const size_t SELF_OFF = 206761536;               // + 10,240,000 B
    const size_t P_OFF    = 217001536;               // + 81,920,000 B  (~299 MB total)
    u16*   AT      = (u16*)(ws + AT_OFF);
    u16*   SPT     = (u16*)(ws + SPT_OFF);
    float* degp    = (float*)(ws + DEGP_OFF);
    float* dinv    = (float*)(ws + DINV_OFF);
    float* selfbuf = (float*)(ws + SELF_OFF);
    float* P       = (float*)(ws + P_OFF);

    k_prep<<<dim3(157, NSP), 256, 0, stream>>>(adj, AT, degp);
    k_dinv<<<40, 256, 0, stream>>>(degp, dinv);
    k_support<<<dim3(157, 4), 256, 0, stream>>>(feat, W, dinv, bias, SPT, selfbuf);
    k_gemm<<<157 * NSP, 256, 0, stream>>>(AT, SPT, P);
    k_out<<<2500, 256, 0, stream>>>(P, selfbuf, dinv, (float*)d_out);
}